// Round 1
// baseline (673.497 us; speedup 1.0000x reference)
//
#include <hip/hip_runtime.h>

typedef _Float16 half8 __attribute__((ext_vector_type(8)));
typedef _Float16 half4v __attribute__((ext_vector_type(4)));
typedef float f32x4 __attribute__((ext_vector_type(4)));

#define NB 4
#define SQ 512
#define CL 3584
#define TT 4096
#define DM 2048
#define NH 16
#define DH 128

// ---------------- cached K/V fp32 -> f16 concat-copy ----------------
__global__ __launch_bounds__(256) void convert_cache(
    const float* __restrict__ ck, const float* __restrict__ cv,
    _Float16* __restrict__ K, _Float16* __restrict__ V)
{
  const long long nvec = (long long)NB * CL * DM / 4;   // float4 count
  const int pb = CL * DM / 4;                           // per-batch float4 count
  for (long long v = (long long)blockIdx.x * blockDim.x + threadIdx.x; v < nvec;
       v += (long long)gridDim.x * blockDim.x) {
    int b = (int)(v / pb);
    long long r = v - (long long)b * pb;
    float4 x = ((const float4*)ck)[v];
    float4 y = ((const float4*)cv)[v];
    half4v hx = { (_Float16)x.x, (_Float16)x.y, (_Float16)x.z, (_Float16)x.w };
    half4v hy = { (_Float16)y.x, (_Float16)y.y, (_Float16)y.z, (_Float16)y.w };
    long long o = (long long)b * (TT * DM / 4) + r;
    ((half4v*)K)[o] = hx;
    ((half4v*)V)[o] = hy;
  }
}

// ---------------- projection GEMM: C = A @ W^T + bias ----------------
// A: [2048, 2048] row-major (fp32 or f16), W: [2048, 2048] fp32 row-major (W[n][k])
// OUT_F32: write fp32 to Cout[m*2048+n]; else f16 with row remap:
//   out_row = (m>>9)*obs + orow + (m&511)
template<bool IN_F16, bool OUT_F32>
__global__ __launch_bounds__(256) void proj_gemm(
    const void* __restrict__ Ain, const float* __restrict__ W,
    const float* __restrict__ bias, void* __restrict__ Cout,
    int obs, int orow, float scale)
{
  __shared__ _Float16 As[2][128][40];
  __shared__ _Float16 Bs[2][128][40];
  const int tid = threadIdx.x;
  const int bm = blockIdx.x, bn = blockIdx.y;
  const int wid = tid >> 6, lane = tid & 63;
  const int wm = wid >> 1, wn = wid & 1;
  const int lr = lane & 15, lg = lane >> 4;
  const int ar = tid >> 1;            // tile row 0..127
  const int ac = (tid & 1) << 4;      // 0 or 16

  f32x4 zero = {0.f, 0.f, 0.f, 0.f};
  f32x4 acc[4][4];
#pragma unroll
  for (int i = 0; i < 4; ++i)
#pragma unroll
    for (int j = 0; j < 4; ++j) acc[i][j] = zero;

  float4 ar4[4], br4[4];
  uint4 ah16[2];

  auto gload = [&](int kt) {
    const int k0 = kt * 32 + ac;
    if constexpr (IN_F16) {
      const _Float16* A = (const _Float16*)Ain + (size_t)(bm * 128 + ar) * DM + k0;
      ah16[0] = *(const uint4*)A;
      ah16[1] = *(const uint4*)(A + 8);
    } else {
      const float* A = (const float*)Ain + (size_t)(bm * 128 + ar) * DM + k0;
      ar4[0] = *(const float4*)A;       ar4[1] = *(const float4*)(A + 4);
      ar4[2] = *(const float4*)(A + 8); ar4[3] = *(const float4*)(A + 12);
    }
    const float* Bp = W + (size_t)(bn * 128 + ar) * DM + k0;
    br4[0] = *(const float4*)Bp;       br4[1] = *(const float4*)(Bp + 4);
    br4[2] = *(const float4*)(Bp + 8); br4[3] = *(const float4*)(Bp + 12);
  };

  auto lwrite = [&](int buf) {
    _Float16* pa = &As[buf][ar][ac];
    if constexpr (IN_F16) {
      *(uint4*)pa = ah16[0];
      *(uint4*)(pa + 8) = ah16[1];
    } else {
      half8 h0 = { (_Float16)ar4[0].x, (_Float16)ar4[0].y, (_Float16)ar4[0].z, (_Float16)ar4[0].w,
                   (_Float16)ar4[1].x, (_Float16)ar4[1].y, (_Float16)ar4[1].z, (_Float16)ar4[1].w };
      half8 h1 = { (_Float16)ar4[2].x, (_Float16)ar4[2].y, (_Float16)ar4[2].z, (_Float16)ar4[2].w,
                   (_Float16)ar4[3].x, (_Float16)ar4[3].y, (_Float16)ar4[3].z, (_Float16)ar4[3].w };
      *(half8*)pa = h0;
      *(half8*)(pa + 8) = h1;
    }
    half8 g0 = { (_Float16)br4[0].x, (_Float16)br4[0].y, (_Float16)br4[0].z, (_Float16)br4[0].w,
                 (_Float16)br4[1].x, (_Float16)br4[1].y, (_Float16)br4[1].z, (_Float16)br4[1].w };
    half8 g1 = { (_Float16)br4[2].x, (_Float16)br4[2].y, (_Float16)br4[2].z, (_Float16)br4[2].w,
                 (_Float16)br4[3].x, (_Float16)br4[3].y, (_Float16)br4[3].z, (_Float16)br4[3].w };
    _Float16* pb = &Bs[buf][ar][ac];
    *(half8*)pb = g0;
    *(half8*)(pb + 8) = g1;
  };

  gload(0);
  lwrite(0);
  const int NKT = DM / 32;  // 64
  for (int kt = 0; kt < NKT; ++kt) {
    __syncthreads();
    const int cur = kt & 1;
    if (kt + 1 < NKT) gload(kt + 1);
    half8 af[4], bf[4];
#pragma unroll
    for (int i = 0; i < 4; ++i) af[i] = *(const half8*)&As[cur][wm * 64 + i * 16 + lr][lg * 8];
#pragma unroll
    for (int j = 0; j < 4; ++j) bf[j] = *(const half8*)&Bs[cur][wn * 64 + j * 16 + lr][lg * 8];
#pragma unroll
    for (int i = 0; i < 4; ++i)
#pragma unroll
      for (int j = 0; j < 4; ++j)
        acc[i][j] = __builtin_amdgcn_mfma_f32_16x16x32_f16(af[i], bf[j], acc[i][j], 0, 0, 0);
    if (kt + 1 < NKT) lwrite((kt + 1) & 1);
  }

#pragma unroll
  for (int i = 0; i < 4; ++i) {
    const int gm0 = bm * 128 + wm * 64 + i * 16 + lg * 4;
#pragma unroll
    for (int j = 0; j < 4; ++j) {
      const int gn = bn * 128 + wn * 64 + j * 16 + lr;
      const float bb = bias[gn];
#pragma unroll
      for (int r = 0; r < 4; ++r) {
        const int m = gm0 + r;
        const float v = (acc[i][j][r] + bb) * scale;
        if constexpr (OUT_F32) {
          ((float*)Cout)[(size_t)m * DM + gn] = v;
        } else {
          const int om = (m >> 9) * obs + orow + (m & 511);
          ((_Float16*)Cout)[(size_t)om * DM + gn] = (_Float16)v;
        }
      }
    }
  }
}

// ---------------- flash attention ----------------
// grid (4 qblocks, 16 heads, 4 batch), 512 threads = 8 waves, wave -> 16 q rows
// Q is pre-scaled by (1/sqrt(128))*log2(e): softmax in exp2 units.
__global__ __launch_bounds__(512) void attn_kernel(
    const _Float16* __restrict__ Qp, const _Float16* __restrict__ Kc,
    const _Float16* __restrict__ Vc, _Float16* __restrict__ AO)
{
  __shared__ _Float16 Ks[32][136];
  __shared__ _Float16 VT[128][40];
  __shared__ _Float16 Ps[8][16][40];

  const int tid = threadIdx.x;
  const int q0 = blockIdx.x * 128;
  const int h = blockIdx.y, b = blockIdx.z;
  const int wid = tid >> 6, lane = tid & 63;
  const int lr = lane & 15, lg = lane >> 4;
  const int qw = q0 + wid * 16;

  // Q fragments in registers (16 rows x 128 d)
  half8 qf[4];
#pragma unroll
  for (int kk = 0; kk < 4; ++kk)
    qf[kk] = *(const half8*)&Qp[(size_t)(b * SQ + qw + lr) * DM + h * DH + kk * 32 + lg * 8];

  f32x4 zero = {0.f, 0.f, 0.f, 0.f};
  f32x4 acc_o[8];
#pragma unroll
  for (int j2 = 0; j2 < 8; ++j2) acc_o[j2] = zero;
  float m_run[4], l_run[4];
#pragma unroll
  for (int r = 0; r < 4; ++r) { m_run[r] = -1e30f; l_run[r] = 0.f; }

  const int nt = (CL + q0 + 128) / 32;
  const int kr = tid >> 4, kc = (tid & 15) << 3;   // K stage: row 0..31, col 0..120
  const int vr = tid & 31, vc = (tid >> 5) << 3;   // V stage: row 0..31, col 0..120

  for (int tt = 0; tt < nt; ++tt) {
    const int t0 = tt * 32;
    __syncthreads();
    {
      const _Float16* kp = &Kc[((size_t)b * TT + t0 + kr) * DM + h * DH + kc];
      uint4 k0 = *(const uint4*)kp;
      const _Float16* vp = &Vc[((size_t)b * TT + t0 + vr) * DM + h * DH + vc];
      uint4 v0 = *(const uint4*)vp;
      *(uint4*)&Ks[kr][kc] = k0;
      const _Float16* tv0 = (const _Float16*)&v0;
#pragma unroll
      for (int c = 0; c < 8; ++c) VT[vc + c][vr] = tv0[c];
    }
    __syncthreads();

    // S = Q K^T  (16 q x 32 t)
    f32x4 s[2];
    s[0] = zero; s[1] = zero;
    half8 kb[2][4];
#pragma unroll
    for (int j = 0; j < 2; ++j)
#pragma unroll
      for (int kk = 0; kk < 4; ++kk)
        kb[j][kk] = *(const half8*)&Ks[j * 16 + lr][kk * 32 + lg * 8];
#pragma unroll
    for (int j = 0; j < 2; ++j)
#pragma unroll
      for (int kk = 0; kk < 4; ++kk)
        s[j] = __builtin_amdgcn_mfma_f32_16x16x32_f16(qf[kk], kb[j][kk], s[j], 0, 0, 0);

    // causal mask (t <= CL + q)
    if (t0 + 31 > CL + qw) {
#pragma unroll
      for (int j = 0; j < 2; ++j)
#pragma unroll
        for (int r = 0; r < 4; ++r) {
          const int t = t0 + j * 16 + lr;
          const int qr = qw + lg * 4 + r;
          if (t > CL + qr) s[j][r] = -1e30f;
        }
    }

    // online softmax per row
#pragma unroll
    for (int r = 0; r < 4; ++r) {
      float mt = fmaxf(s[0][r], s[1][r]);
      mt = fmaxf(mt, __shfl_xor(mt, 1));
      mt = fmaxf(mt, __shfl_xor(mt, 2));
      mt = fmaxf(mt, __shfl_xor(mt, 4));
      mt = fmaxf(mt, __shfl_xor(mt, 8));
      const float mo = m_run[r];
      const float mn = fmaxf(mo, mt);
      const float fsc = exp2f(mo - mn);
      m_run[r] = mn;
      const float p0 = exp2f(s[0][r] - mn);
      const float p1 = exp2f(s[1][r] - mn);
      float ps = p0 + p1;
      ps += __shfl_xor(ps, 1);
      ps += __shfl_xor(ps, 2);
      ps += __shfl_xor(ps, 4);
      ps += __shfl_xor(ps, 8);
      l_run[r] = l_run[r] * fsc + ps;
#pragma unroll
      for (int j2 = 0; j2 < 8; ++j2) acc_o[j2][r] *= fsc;
      Ps[wid][lg * 4 + r][lr] = (_Float16)p0;
      Ps[wid][lg * 4 + r][16 + lr] = (_Float16)p1;
    }

    // O += P V  (16 q x 128 d)
    half8 pa = *(const half8*)&Ps[wid][lr][lg * 8];
#pragma unroll
    for (int j2 = 0; j2 < 8; ++j2) {
      half8 vb = *(const half8*)&VT[j2 * 16 + lr][lg * 8];
      acc_o[j2] = __builtin_amdgcn_mfma_f32_16x16x32_f16(pa, vb, acc_o[j2], 0, 0, 0);
    }
  }

#pragma unroll
  for (int r = 0; r < 4; ++r) {
    const float inv = 1.0f / l_run[r];
    const int qr = qw + lg * 4 + r;
#pragma unroll
    for (int j2 = 0; j2 < 8; ++j2) {
      AO[(size_t)(b * SQ + qr) * DM + h * DH + j2 * 16 + lr] =
          (_Float16)(acc_o[j2][r] * inv);
    }
  }
}

extern "C" void kernel_launch(void* const* d_in, const int* in_sizes, int n_in,
                              void* d_out, int out_size, void* d_ws, size_t ws_size,
                              hipStream_t stream) {
  const float* query = (const float*)d_in[0];
  const float* key   = (const float*)d_in[1];
  const float* value = (const float*)d_in[2];
  const float* ck    = (const float*)d_in[3];
  const float* cv    = (const float*)d_in[4];
  const float* wq = (const float*)d_in[5];
  const float* bq = (const float*)d_in[6];
  const float* wk = (const float*)d_in[7];
  const float* bk = (const float*)d_in[8];
  const float* wv = (const float*)d_in[9];
  const float* bv = (const float*)d_in[10];
  const float* wo = (const float*)d_in[11];
  const float* bo = (const float*)d_in[12];

  char* ws = (char*)d_ws;
  _Float16* Kc = (_Float16*)ws;                          // 64 MiB: [4][4096][2048]
  _Float16* Vc = (_Float16*)(ws + 67108864);             // 64 MiB
  _Float16* Qp = (_Float16*)(ws + 134217728);            // 8 MiB: [2048][2048]
  _Float16* AO = (_Float16*)(ws + 142606336);            // 8 MiB

  convert_cache<<<dim3(1024), dim3(256), 0, stream>>>(ck, cv, Kc, Vc);

  const float qscale = 0.08838834764831845f * 1.4426950408889634f;
  proj_gemm<false, false><<<dim3(16, 16), dim3(256), 0, stream>>>(
      (const void*)query, wq, bq, (void*)Qp, 512, 0, qscale);
  proj_gemm<false, false><<<dim3(16, 16), dim3(256), 0, stream>>>(
      (const void*)key, wk, bk, (void*)Kc, 4096, 3584, 1.0f);
  proj_gemm<false, false><<<dim3(16, 16), dim3(256), 0, stream>>>(
      (const void*)value, wv, bv, (void*)Vc, 4096, 3584, 1.0f);

  attn_kernel<<<dim3(4, 16, 4), dim3(512), 0, stream>>>(Qp, Kc, Vc, AO);

  proj_gemm<true, true><<<dim3(16, 16), dim3(256), 0, stream>>>(
      (const void*)AO, wo, bo, d_out, 512, 0, 1.0f);
}

// Round 2
// 439.277 us; speedup vs baseline: 1.5332x; 1.5332x over previous
//
#include <hip/hip_runtime.h>

typedef _Float16 half8 __attribute__((ext_vector_type(8)));
typedef _Float16 half4v __attribute__((ext_vector_type(4)));
typedef float f32x4 __attribute__((ext_vector_type(4)));

#define NB 4
#define SQ 512
#define CL 3584
#define TT 4096
#define DM 2048
#define NH 16
#define DH 128

// ---------------- cached K fp32 -> f16 linear convert ----------------
__global__ __launch_bounds__(256) void convert_K(
    const float* __restrict__ ck, _Float16* __restrict__ K)
{
  const long long nvec = (long long)NB * CL * DM / 4;
  const int pb = CL * DM / 4;
  for (long long v = (long long)blockIdx.x * blockDim.x + threadIdx.x; v < nvec;
       v += (long long)gridDim.x * blockDim.x) {
    int b = (int)(v / pb);
    long long r = v - (long long)b * pb;
    float4 x = ((const float4*)ck)[v];
    half4v hx = { (_Float16)x.x, (_Float16)x.y, (_Float16)x.z, (_Float16)x.w };
    ((half4v*)K)[(long long)b * (TT * DM / 4) + r] = hx;
  }
}

// ---------------- cached V fp32 -> f16 transpose: Vt[b][h][d][t] ----------------
__global__ __launch_bounds__(256) void transpose_V(
    const float* __restrict__ cv, _Float16* __restrict__ Vt)
{
  __shared__ _Float16 T[64][70];
  const int t0 = blockIdx.x * 64;
  const int dm0 = blockIdx.y * 64;
  const int b = blockIdx.z;
  const int tid = threadIdx.x;
  {
    const int tr = tid >> 2, c0 = (tid & 3) * 16;
    const float* src = cv + ((size_t)b * CL + t0 + tr) * DM + dm0 + c0;
    float4 a0 = ((const float4*)src)[0];
    float4 a1 = ((const float4*)src)[1];
    float4 a2 = ((const float4*)src)[2];
    float4 a3 = ((const float4*)src)[3];
    half8 h0 = { (_Float16)a0.x, (_Float16)a0.y, (_Float16)a0.z, (_Float16)a0.w,
                 (_Float16)a1.x, (_Float16)a1.y, (_Float16)a1.z, (_Float16)a1.w };
    half8 h1 = { (_Float16)a2.x, (_Float16)a2.y, (_Float16)a2.z, (_Float16)a2.w,
                 (_Float16)a3.x, (_Float16)a3.y, (_Float16)a3.z, (_Float16)a3.w };
    *(half8*)&T[tr][c0] = h0;
    *(half8*)&T[tr][c0 + 8] = h1;
  }
  __syncthreads();
  {
    const int dl = tid >> 2, tc = (tid & 3) * 16;
    const int h = dm0 >> 7, d = (dm0 & 127) + dl;
    half8 o0, o1;
#pragma unroll
    for (int i = 0; i < 8; ++i) o0[i] = T[tc + i][dl];
#pragma unroll
    for (int i = 0; i < 8; ++i) o1[i] = T[tc + 8 + i][dl];
    _Float16* dst = Vt + ((size_t)(b * NH + h) * DH + d) * TT + t0 + tc;
    *(half8*)dst = o0;
    *(half8*)(dst + 8) = o1;
  }
}

// ---------------- fused QKV projection GEMM (z selects which) ----------------
__global__ __launch_bounds__(256) void qkv_gemm(
    const float* __restrict__ qin, const float* __restrict__ kin, const float* __restrict__ vin,
    const float* __restrict__ wq, const float* __restrict__ wk, const float* __restrict__ wv,
    const float* __restrict__ bq, const float* __restrict__ bk, const float* __restrict__ bv,
    _Float16* __restrict__ Qp, _Float16* __restrict__ Kc, _Float16* __restrict__ Vt)
{
  const int z = blockIdx.z;
  const float* Ain  = z == 0 ? qin : z == 1 ? kin : vin;
  const float* W    = z == 0 ? wq  : z == 1 ? wk  : wv;
  const float* bias = z == 0 ? bq  : z == 1 ? bk  : bv;

  __shared__ _Float16 As[2][128][40];
  __shared__ _Float16 Bs[2][128][40];
  const int tid = threadIdx.x;
  const int bm = blockIdx.x, bn = blockIdx.y;
  const int wid = tid >> 6, lane = tid & 63;
  const int wm = wid >> 1, wn = wid & 1;
  const int lr = lane & 15, lg = lane >> 4;
  const int ar = tid >> 1;
  const int ac = (tid & 1) << 4;

  f32x4 zero = {0.f, 0.f, 0.f, 0.f};
  f32x4 acc[4][4];
#pragma unroll
  for (int i = 0; i < 4; ++i)
#pragma unroll
    for (int j = 0; j < 4; ++j) acc[i][j] = zero;

  float4 ar4[4], br4[4];

  auto gload = [&](int kt) {
    const int k0 = kt * 32 + ac;
    const float* A = Ain + (size_t)(bm * 128 + ar) * DM + k0;
    ar4[0] = *(const float4*)A;       ar4[1] = *(const float4*)(A + 4);
    ar4[2] = *(const float4*)(A + 8); ar4[3] = *(const float4*)(A + 12);
    const float* Bp = W + (size_t)(bn * 128 + ar) * DM + k0;
    br4[0] = *(const float4*)Bp;       br4[1] = *(const float4*)(Bp + 4);
    br4[2] = *(const float4*)(Bp + 8); br4[3] = *(const float4*)(Bp + 12);
  };
  auto lwrite = [&](int buf) {
    half8 h0 = { (_Float16)ar4[0].x, (_Float16)ar4[0].y, (_Float16)ar4[0].z, (_Float16)ar4[0].w,
                 (_Float16)ar4[1].x, (_Float16)ar4[1].y, (_Float16)ar4[1].z, (_Float16)ar4[1].w };
    half8 h1 = { (_Float16)ar4[2].x, (_Float16)ar4[2].y, (_Float16)ar4[2].z, (_Float16)ar4[2].w,
                 (_Float16)ar4[3].x, (_Float16)ar4[3].y, (_Float16)ar4[3].z, (_Float16)ar4[3].w };
    _Float16* pa = &As[buf][ar][ac];
    *(half8*)pa = h0; *(half8*)(pa + 8) = h1;
    half8 g0 = { (_Float16)br4[0].x, (_Float16)br4[0].y, (_Float16)br4[0].z, (_Float16)br4[0].w,
                 (_Float16)br4[1].x, (_Float16)br4[1].y, (_Float16)br4[1].z, (_Float16)br4[1].w };
    half8 g1 = { (_Float16)br4[2].x, (_Float16)br4[2].y, (_Float16)br4[2].z, (_Float16)br4[2].w,
                 (_Float16)br4[3].x, (_Float16)br4[3].y, (_Float16)br4[3].z, (_Float16)br4[3].w };
    _Float16* pb = &Bs[buf][ar][ac];
    *(half8*)pb = g0; *(half8*)(pb + 8) = g1;
  };

  gload(0);
  lwrite(0);
  const int NKT = DM / 32;
  for (int kt = 0; kt < NKT; ++kt) {
    __syncthreads();
    const int cur = kt & 1;
    if (kt + 1 < NKT) gload(kt + 1);
    half8 af[4], bf[4];
#pragma unroll
    for (int i = 0; i < 4; ++i) af[i] = *(const half8*)&As[cur][wm * 64 + i * 16 + lr][lg * 8];
#pragma unroll
    for (int j = 0; j < 4; ++j) bf[j] = *(const half8*)&Bs[cur][wn * 64 + j * 16 + lr][lg * 8];
#pragma unroll
    for (int i = 0; i < 4; ++i)
#pragma unroll
      for (int j = 0; j < 4; ++j)
        acc[i][j] = __builtin_amdgcn_mfma_f32_16x16x32_f16(af[i], bf[j], acc[i][j], 0, 0, 0);
    if (kt + 1 < NKT) lwrite((kt + 1) & 1);
  }

  const float qscale = 0.08838834764831845f * 1.4426950408889634f;
#pragma unroll
  for (int i = 0; i < 4; ++i) {
    const int m0 = bm * 128 + wm * 64 + i * 16 + lg * 4;
#pragma unroll
    for (int j = 0; j < 4; ++j) {
      const int gn = bn * 128 + wn * 64 + j * 16 + lr;
      const float bb = bias[gn];
      if (z == 2) {
        half4v hv;
#pragma unroll
        for (int r = 0; r < 4; ++r) hv[r] = (_Float16)(acc[i][j][r] + bb);
        const int b = m0 >> 9, t = CL + (m0 & 511);
        const int h = gn >> 7, d = gn & 127;
        *(half4v*)&Vt[((size_t)(b * NH + h) * DH + d) * TT + t] = hv;
      } else if (z == 0) {
#pragma unroll
        for (int r = 0; r < 4; ++r)
          Qp[(size_t)(m0 + r) * DM + gn] = (_Float16)((acc[i][j][r] + bb) * qscale);
      } else {
        const int b = m0 >> 9;
#pragma unroll
        for (int r = 0; r < 4; ++r)
          Kc[((size_t)b * TT + CL + ((m0 + r) & 511)) * DM + gn] = (_Float16)(acc[i][j][r] + bb);
      }
    }
  }
}

// ---------------- O projection GEMM (f16 A, f32 out) ----------------
__global__ __launch_bounds__(256) void o_gemm(
    const _Float16* __restrict__ Ain, const float* __restrict__ W,
    const float* __restrict__ bias, float* __restrict__ Cout)
{
  __shared__ _Float16 As[2][128][40];
  __shared__ _Float16 Bs[2][128][40];
  const int tid = threadIdx.x;
  const int bm = blockIdx.x, bn = blockIdx.y;
  const int wid = tid >> 6, lane = tid & 63;
  const int wm = wid >> 1, wn = wid & 1;
  const int lr = lane & 15, lg = lane >> 4;
  const int ar = tid >> 1;
  const int ac = (tid & 1) << 4;

  f32x4 zero = {0.f, 0.f, 0.f, 0.f};
  f32x4 acc[4][4];
#pragma unroll
  for (int i = 0; i < 4; ++i)
#pragma unroll
    for (int j = 0; j < 4; ++j) acc[i][j] = zero;

  uint4 ah16[2];
  float4 br4[4];
  auto gload = [&](int kt) {
    const int k0 = kt * 32 + ac;
    const _Float16* A = Ain + (size_t)(bm * 128 + ar) * DM + k0;
    ah16[0] = *(const uint4*)A;
    ah16[1] = *(const uint4*)(A + 8);
    const float* Bp = W + (size_t)(bn * 128 + ar) * DM + k0;
    br4[0] = *(const float4*)Bp;       br4[1] = *(const float4*)(Bp + 4);
    br4[2] = *(const float4*)(Bp + 8); br4[3] = *(const float4*)(Bp + 12);
  };
  auto lwrite = [&](int buf) {
    _Float16* pa = &As[buf][ar][ac];
    *(uint4*)pa = ah16[0];
    *(uint4*)(pa + 8) = ah16[1];
    half8 g0 = { (_Float16)br4[0].x, (_Float16)br4[0].y, (_Float16)br4[0].z, (_Float16)br4[0].w,
                 (_Float16)br4[1].x, (_Float16)br4[1].y, (_Float16)br4[1].z, (_Float16)br4[1].w };
    half8 g1 = { (_Float16)br4[2].x, (_Float16)br4[2].y, (_Float16)br4[2].z, (_Float16)br4[2].w,
                 (_Float16)br4[3].x, (_Float16)br4[3].y, (_Float16)br4[3].z, (_Float16)br4[3].w };
    _Float16* pb = &Bs[buf][ar][ac];
    *(half8*)pb = g0; *(half8*)(pb + 8) = g1;
  };

  gload(0);
  lwrite(0);
  const int NKT = DM / 32;
  for (int kt = 0; kt < NKT; ++kt) {
    __syncthreads();
    const int cur = kt & 1;
    if (kt + 1 < NKT) gload(kt + 1);
    half8 af[4], bf[4];
#pragma unroll
    for (int i = 0; i < 4; ++i) af[i] = *(const half8*)&As[cur][wm * 64 + i * 16 + lr][lg * 8];
#pragma unroll
    for (int j = 0; j < 4; ++j) bf[j] = *(const half8*)&Bs[cur][wn * 64 + j * 16 + lr][lg * 8];
#pragma unroll
    for (int i = 0; i < 4; ++i)
#pragma unroll
      for (int j = 0; j < 4; ++j)
        acc[i][j] = __builtin_amdgcn_mfma_f32_16x16x32_f16(af[i], bf[j], acc[i][j], 0, 0, 0);
    if (kt + 1 < NKT) lwrite((kt + 1) & 1);
  }

#pragma unroll
  for (int i = 0; i < 4; ++i) {
    const int m0 = bm * 128 + wm * 64 + i * 16 + lg * 4;
#pragma unroll
    for (int j = 0; j < 4; ++j) {
      const int gn = bn * 128 + wn * 64 + j * 16 + lr;
      const float bb = bias[gn];
#pragma unroll
      for (int r = 0; r < 4; ++r)
        Cout[(size_t)(m0 + r) * DM + gn] = acc[i][j][r] + bb;
    }
  }
}

// ---------------- flash attention (swapped QK^T, V^T global, double-buffered) ----------------
// grid (4 qblocks, 16 heads, 4 batch), 512 threads = 8 waves, wave -> 16 q rows.
// Q pre-scaled by (1/sqrt(128))*log2(e).
__global__ __launch_bounds__(512) void attn_kernel(
    const _Float16* __restrict__ Qp, const _Float16* __restrict__ Kc,
    const _Float16* __restrict__ Vt, _Float16* __restrict__ AO)
{
  __shared__ _Float16 Ks[2][64][136];
  __shared__ _Float16 VT[2][128][72];
  __shared__ _Float16 Ps[8][16][72];

  const int tid = threadIdx.x;
  const int q0 = blockIdx.x * 128;
  const int h = blockIdx.y, b = blockIdx.z;
  const int wid = tid >> 6, lane = tid & 63;
  const int lr = lane & 15, lg = lane >> 4;
  const int qw = q0 + wid * 16;

  // Q fragments (B-operand): lane holds Q[qw+lr][kk*32+lg*8 .. +7]
  half8 qf[4];
#pragma unroll
  for (int kk = 0; kk < 4; ++kk)
    qf[kk] = *(const half8*)&Qp[(size_t)(b * SQ + qw + lr) * DM + h * DH + kk * 32 + lg * 8];

  f32x4 zero = {0.f, 0.f, 0.f, 0.f};
  f32x4 acc_t[8];   // O^T: d = dblk*16 + lg*4 + r, q = lr
#pragma unroll
  for (int d = 0; d < 8; ++d) acc_t[d] = zero;
  float m_run = -1e30f, l_run = 0.f;

  const int nt = (CL + q0 + 128) / 64;
  const int kr = tid >> 4, kc = (tid & 15) << 3;   // K: 32 rows/pass, 16B each
  const int vd = tid >> 3, vcol = (tid & 7) << 3;  // V^T: 64 rows/pass, 16B each
  const _Float16* Kbase = Kc + (size_t)b * TT * DM + h * DH;
  const _Float16* Vbase = Vt + (size_t)(b * NH + h) * DH * TT;

  uint4 kreg0, kreg1, vreg0, vreg1;
  auto gload_t = [&](int tt) {
    const int t0 = tt * 64;
    kreg0 = *(const uint4*)(Kbase + (size_t)(t0 + kr) * DM + kc);
    kreg1 = *(const uint4*)(Kbase + (size_t)(t0 + kr + 32) * DM + kc);
    vreg0 = *(const uint4*)(Vbase + (size_t)vd * TT + t0 + vcol);
    vreg1 = *(const uint4*)(Vbase + (size_t)(vd + 64) * TT + t0 + vcol);
  };
  auto lwrite_t = [&](int buf) {
    *(uint4*)&Ks[buf][kr][kc] = kreg0;
    *(uint4*)&Ks[buf][kr + 32][kc] = kreg1;
    *(uint4*)&VT[buf][vd][vcol] = vreg0;
    *(uint4*)&VT[buf][vd + 64][vcol] = vreg1;
  };

  gload_t(0);
  lwrite_t(0);

  for (int tt = 0; tt < nt; ++tt) {
    const int t0 = tt * 64;
    const int cur = tt & 1;
    __syncthreads();
    if (tt + 1 < nt) gload_t(tt + 1);

    // S^T = K Q^T : rows t (regs), cols q (lanes)
    f32x4 s[4];
#pragma unroll
    for (int j = 0; j < 4; ++j) {
      s[j] = zero;
      half8 kb[4];
#pragma unroll
      for (int kk = 0; kk < 4; ++kk)
        kb[kk] = *(const half8*)&Ks[cur][j * 16 + lr][kk * 32 + lg * 8];
#pragma unroll
      for (int kk = 0; kk < 4; ++kk)
        s[j] = __builtin_amdgcn_mfma_f32_16x16x32_f16(kb[kk], qf[kk], s[j], 0, 0, 0);
    }

    // causal mask: t > CL + q  (q = qw + lr, t = t0 + j*16 + lg*4 + r)
    if (t0 + 63 > CL + qw) {
#pragma unroll
      for (int j = 0; j < 4; ++j)
#pragma unroll
        for (int r = 0; r < 4; ++r)
          if (t0 + j * 16 + lg * 4 + r > CL + qw + lr) s[j][r] = -1e30f;
    }

    // online softmax (per lane: one q row; t spread over regs + lane groups)
    float mt = s[0][0];
#pragma unroll
    for (int j = 0; j < 4; ++j)
#pragma unroll
      for (int r = 0; r < 4; ++r) mt = fmaxf(mt, s[j][r]);
    mt = fmaxf(mt, __shfl_xor(mt, 16));
    mt = fmaxf(mt, __shfl_xor(mt, 32));
    const float mn = fmaxf(m_run, mt);
    const float fsc = exp2f(m_run - mn);
    float p[4][4];
    float ps = 0.f;
#pragma unroll
    for (int j = 0; j < 4; ++j)
#pragma unroll
      for (int r = 0; r < 4; ++r) {
        p[j][r] = exp2f(s[j][r] - mn);
        ps += p[j][r];
      }
    ps += __shfl_xor(ps, 16);
    ps += __shfl_xor(ps, 32);
    l_run = l_run * fsc + ps;
    m_run = mn;

    // write P^T fragments: Ps[wid][q=lr][t], packed half4 over r
#pragma unroll
    for (int j = 0; j < 4; ++j) {
      half4v hp = { (_Float16)p[j][0], (_Float16)p[j][1], (_Float16)p[j][2], (_Float16)p[j][3] };
      *(half4v*)&Ps[wid][lr][j * 16 + lg * 4] = hp;
    }

    // rescale O^T
#pragma unroll
    for (int d = 0; d < 8; ++d)
#pragma unroll
      for (int r = 0; r < 4; ++r) acc_t[d][r] *= fsc;

    // O^T += V^T P^T
#pragma unroll
    for (int tf = 0; tf < 2; ++tf) {
      half8 pf = *(const half8*)&Ps[wid][lr][tf * 32 + lg * 8];
#pragma unroll
      for (int d = 0; d < 8; ++d) {
        half8 vf = *(const half8*)&VT[cur][d * 16 + lr][tf * 32 + lg * 8];
        acc_t[d] = __builtin_amdgcn_mfma_f32_16x16x32_f16(vf, pf, acc_t[d], 0, 0, 0);
      }
    }

    if (tt + 1 < nt) lwrite_t(cur ^ 1);
  }

  const float inv = 1.0f / l_run;
#pragma unroll
  for (int d = 0; d < 8; ++d) {
    half4v hv;
#pragma unroll
    for (int r = 0; r < 4; ++r) hv[r] = (_Float16)(acc_t[d][r] * inv);
    *(half4v*)&AO[(size_t)(b * SQ + qw + lr) * DM + h * DH + d * 16 + lg * 4] = hv;
  }
}

extern "C" void kernel_launch(void* const* d_in, const int* in_sizes, int n_in,
                              void* d_out, int out_size, void* d_ws, size_t ws_size,
                              hipStream_t stream) {
  const float* query = (const float*)d_in[0];
  const float* key   = (const float*)d_in[1];
  const float* value = (const float*)d_in[2];
  const float* ck    = (const float*)d_in[3];
  const float* cv    = (const float*)d_in[4];
  const float* wq = (const float*)d_in[5];
  const float* bq = (const float*)d_in[6];
  const float* wk = (const float*)d_in[7];
  const float* bk = (const float*)d_in[8];
  const float* wv = (const float*)d_in[9];
  const float* bv = (const float*)d_in[10];
  const float* wo = (const float*)d_in[11];
  const float* bo = (const float*)d_in[12];

  char* ws = (char*)d_ws;
  _Float16* Kc = (_Float16*)ws;                 // 64 MiB: [4][4096][2048]
  _Float16* Vt = (_Float16*)(ws + 67108864);    // 64 MiB: [4][16][128][4096]
  _Float16* Qp = (_Float16*)(ws + 134217728);   // 8 MiB
  _Float16* AO = (_Float16*)(ws + 142606336);   // 8 MiB

  convert_K<<<dim3(2048), dim3(256), 0, stream>>>(ck, Kc);
  transpose_V<<<dim3(CL / 64, DM / 64, NB), dim3(256), 0, stream>>>(cv, Vt);
  qkv_gemm<<<dim3(16, 16, 3), dim3(256), 0, stream>>>(
      query, key, value, wq, wk, wv, bq, bk, bv, Qp, Kc, Vt);
  attn_kernel<<<dim3(4, 16, 4), dim3(512), 0, stream>>>(Qp, Kc, Vt, AO);
  o_gemm<<<dim3(16, 16), dim3(256), 0, stream>>>(AO, wo, bo, (float*)d_out);
}

// Round 3
// 404.156 us; speedup vs baseline: 1.6664x; 1.0869x over previous
//
#include <hip/hip_runtime.h>

typedef _Float16 half8 __attribute__((ext_vector_type(8)));
typedef _Float16 half4v __attribute__((ext_vector_type(4)));
typedef float f32x4 __attribute__((ext_vector_type(4)));

#define NB 4
#define SQ 512
#define CL 3584
#define TT 4096
#define DM 2048
#define NH 16
#define DH 128

// XOR swizzles on half-index (16B granule spread across 8 slots per 8 rows)
#define KSW(row, col) ((((row) * 128) + (col)) ^ ((((row) & 7) << 3)))
#define VSW(row, col) ((((row) * 64) + (col)) ^ ((((row) & 7) << 3)))
#define PSW(row, col) ((((row) * 64) + (col)) ^ ((((row) & 7) << 3)))

// ---------------- cached K fp32 -> f16 linear convert ----------------
__global__ __launch_bounds__(256) void convert_K(
    const float* __restrict__ ck, _Float16* __restrict__ K)
{
  const long long nvec = (long long)NB * CL * DM / 4;
  const int pb = CL * DM / 4;
  for (long long v = (long long)blockIdx.x * blockDim.x + threadIdx.x; v < nvec;
       v += (long long)gridDim.x * blockDim.x) {
    int b = (int)(v / pb);
    long long r = v - (long long)b * pb;
    float4 x = ((const float4*)ck)[v];
    half4v hx = { (_Float16)x.x, (_Float16)x.y, (_Float16)x.z, (_Float16)x.w };
    ((half4v*)K)[(long long)b * (TT * DM / 4) + r] = hx;
  }
}

// ---------------- cached V fp32 -> f16 transpose: Vt[b][h][d][t] ----------------
__global__ __launch_bounds__(256) void transpose_V(
    const float* __restrict__ cv, _Float16* __restrict__ Vt)
{
  __shared__ _Float16 T[64][70];
  const int t0 = blockIdx.x * 64;
  const int dm0 = blockIdx.y * 64;
  const int b = blockIdx.z;
  const int tid = threadIdx.x;
  {
    const int tr = tid >> 2, c0 = (tid & 3) * 16;
    const float* src = cv + ((size_t)b * CL + t0 + tr) * DM + dm0 + c0;
    float4 a0 = ((const float4*)src)[0];
    float4 a1 = ((const float4*)src)[1];
    float4 a2 = ((const float4*)src)[2];
    float4 a3 = ((const float4*)src)[3];
    half8 h0 = { (_Float16)a0.x, (_Float16)a0.y, (_Float16)a0.z, (_Float16)a0.w,
                 (_Float16)a1.x, (_Float16)a1.y, (_Float16)a1.z, (_Float16)a1.w };
    half8 h1 = { (_Float16)a2.x, (_Float16)a2.y, (_Float16)a2.z, (_Float16)a2.w,
                 (_Float16)a3.x, (_Float16)a3.y, (_Float16)a3.z, (_Float16)a3.w };
    *(half8*)&T[tr][c0] = h0;
    *(half8*)&T[tr][c0 + 8] = h1;
  }
  __syncthreads();
  {
    const int dl = tid >> 2, tc = (tid & 3) * 16;
    const int h = dm0 >> 7, d = (dm0 & 127) + dl;
    half8 o0, o1;
#pragma unroll
    for (int i = 0; i < 8; ++i) o0[i] = T[tc + i][dl];
#pragma unroll
    for (int i = 0; i < 8; ++i) o1[i] = T[tc + 8 + i][dl];
    _Float16* dst = Vt + ((size_t)(b * NH + h) * DH + d) * TT + t0 + tc;
    *(half8*)dst = o0;
    *(half8*)(dst + 8) = o1;
  }
}

// ---------------- fused QKV projection GEMM (z selects which) ----------------
__global__ __launch_bounds__(256) void qkv_gemm(
    const float* __restrict__ qin, const float* __restrict__ kin, const float* __restrict__ vin,
    const float* __restrict__ wq, const float* __restrict__ wk, const float* __restrict__ wv,
    const float* __restrict__ bq, const float* __restrict__ bk, const float* __restrict__ bv,
    _Float16* __restrict__ Qp, _Float16* __restrict__ Kc, _Float16* __restrict__ Vt)
{
  const int z = blockIdx.z;
  const float* Ain  = z == 0 ? qin : z == 1 ? kin : vin;
  const float* W    = z == 0 ? wq  : z == 1 ? wk  : wv;
  const float* bias = z == 0 ? bq  : z == 1 ? bk  : bv;

  __shared__ _Float16 As[2][128][40];
  __shared__ _Float16 Bs[2][128][40];
  const int tid = threadIdx.x;
  const int bm = blockIdx.x, bn = blockIdx.y;
  const int wid = tid >> 6, lane = tid & 63;
  const int wm = wid >> 1, wn = wid & 1;
  const int lr = lane & 15, lg = lane >> 4;
  const int ar = tid >> 1;
  const int ac = (tid & 1) << 4;

  f32x4 zero = {0.f, 0.f, 0.f, 0.f};
  f32x4 acc[4][4];
#pragma unroll
  for (int i = 0; i < 4; ++i)
#pragma unroll
    for (int j = 0; j < 4; ++j) acc[i][j] = zero;

  float4 ar4[4], br4[4];

  auto gload = [&](int kt) {
    const int k0 = kt * 32 + ac;
    const float* A = Ain + (size_t)(bm * 128 + ar) * DM + k0;
    ar4[0] = *(const float4*)A;       ar4[1] = *(const float4*)(A + 4);
    ar4[2] = *(const float4*)(A + 8); ar4[3] = *(const float4*)(A + 12);
    const float* Bp = W + (size_t)(bn * 128 + ar) * DM + k0;
    br4[0] = *(const float4*)Bp;       br4[1] = *(const float4*)(Bp + 4);
    br4[2] = *(const float4*)(Bp + 8); br4[3] = *(const float4*)(Bp + 12);
  };
  auto lwrite = [&](int buf) {
    half8 h0 = { (_Float16)ar4[0].x, (_Float16)ar4[0].y, (_Float16)ar4[0].z, (_Float16)ar4[0].w,
                 (_Float16)ar4[1].x, (_Float16)ar4[1].y, (_Float16)ar4[1].z, (_Float16)ar4[1].w };
    half8 h1 = { (_Float16)ar4[2].x, (_Float16)ar4[2].y, (_Float16)ar4[2].z, (_Float16)ar4[2].w,
                 (_Float16)ar4[3].x, (_Float16)ar4[3].y, (_Float16)ar4[3].z, (_Float16)ar4[3].w };
    _Float16* pa = &As[buf][ar][ac];
    *(half8*)pa = h0; *(half8*)(pa + 8) = h1;
    half8 g0 = { (_Float16)br4[0].x, (_Float16)br4[0].y, (_Float16)br4[0].z, (_Float16)br4[0].w,
                 (_Float16)br4[1].x, (_Float16)br4[1].y, (_Float16)br4[1].z, (_Float16)br4[1].w };
    half8 g1 = { (_Float16)br4[2].x, (_Float16)br4[2].y, (_Float16)br4[2].z, (_Float16)br4[2].w,
                 (_Float16)br4[3].x, (_Float16)br4[3].y, (_Float16)br4[3].z, (_Float16)br4[3].w };
    _Float16* pb = &Bs[buf][ar][ac];
    *(half8*)pb = g0; *(half8*)(pb + 8) = g1;
  };

  gload(0);
  lwrite(0);
  const int NKT = DM / 32;
  for (int kt = 0; kt < NKT; ++kt) {
    __syncthreads();
    const int cur = kt & 1;
    if (kt + 1 < NKT) gload(kt + 1);
    half8 af[4], bf[4];
#pragma unroll
    for (int i = 0; i < 4; ++i) af[i] = *(const half8*)&As[cur][wm * 64 + i * 16 + lr][lg * 8];
#pragma unroll
    for (int j = 0; j < 4; ++j) bf[j] = *(const half8*)&Bs[cur][wn * 64 + j * 16 + lr][lg * 8];
#pragma unroll
    for (int i = 0; i < 4; ++i)
#pragma unroll
      for (int j = 0; j < 4; ++j)
        acc[i][j] = __builtin_amdgcn_mfma_f32_16x16x32_f16(af[i], bf[j], acc[i][j], 0, 0, 0);
    if (kt + 1 < NKT) lwrite((kt + 1) & 1);
  }

  const float qscale = 0.08838834764831845f * 1.4426950408889634f;
#pragma unroll
  for (int i = 0; i < 4; ++i) {
    const int m0 = bm * 128 + wm * 64 + i * 16 + lg * 4;
#pragma unroll
    for (int j = 0; j < 4; ++j) {
      const int gn = bn * 128 + wn * 64 + j * 16 + lr;
      const float bb = bias[gn];
      if (z == 2) {
        half4v hv;
#pragma unroll
        for (int r = 0; r < 4; ++r) hv[r] = (_Float16)(acc[i][j][r] + bb);
        const int b = m0 >> 9, t = CL + (m0 & 511);
        const int h = gn >> 7, d = gn & 127;
        *(half4v*)&Vt[((size_t)(b * NH + h) * DH + d) * TT + t] = hv;
      } else if (z == 0) {
#pragma unroll
        for (int r = 0; r < 4; ++r)
          Qp[(size_t)(m0 + r) * DM + gn] = (_Float16)((acc[i][j][r] + bb) * qscale);
      } else {
        const int b = m0 >> 9;
#pragma unroll
        for (int r = 0; r < 4; ++r)
          Kc[((size_t)b * TT + CL + ((m0 + r) & 511)) * DM + gn] = (_Float16)(acc[i][j][r] + bb);
      }
    }
  }
}

// ---------------- O projection GEMM (f16 A, f32 out) ----------------
__global__ __launch_bounds__(256) void o_gemm(
    const _Float16* __restrict__ Ain, const float* __restrict__ W,
    const float* __restrict__ bias, float* __restrict__ Cout)
{
  __shared__ _Float16 As[2][128][40];
  __shared__ _Float16 Bs[2][128][40];
  const int tid = threadIdx.x;
  const int bm = blockIdx.x, bn = blockIdx.y;
  const int wid = tid >> 6, lane = tid & 63;
  const int wm = wid >> 1, wn = wid & 1;
  const int lr = lane & 15, lg = lane >> 4;
  const int ar = tid >> 1;
  const int ac = (tid & 1) << 4;

  f32x4 zero = {0.f, 0.f, 0.f, 0.f};
  f32x4 acc[4][4];
#pragma unroll
  for (int i = 0; i < 4; ++i)
#pragma unroll
    for (int j = 0; j < 4; ++j) acc[i][j] = zero;

  uint4 ah16[2];
  float4 br4[4];
  auto gload = [&](int kt) {
    const int k0 = kt * 32 + ac;
    const _Float16* A = Ain + (size_t)(bm * 128 + ar) * DM + k0;
    ah16[0] = *(const uint4*)A;
    ah16[1] = *(const uint4*)(A + 8);
    const float* Bp = W + (size_t)(bn * 128 + ar) * DM + k0;
    br4[0] = *(const float4*)Bp;       br4[1] = *(const float4*)(Bp + 4);
    br4[2] = *(const float4*)(Bp + 8); br4[3] = *(const float4*)(Bp + 12);
  };
  auto lwrite = [&](int buf) {
    _Float16* pa = &As[buf][ar][ac];
    *(uint4*)pa = ah16[0];
    *(uint4*)(pa + 8) = ah16[1];
    half8 g0 = { (_Float16)br4[0].x, (_Float16)br4[0].y, (_Float16)br4[0].z, (_Float16)br4[0].w,
                 (_Float16)br4[1].x, (_Float16)br4[1].y, (_Float16)br4[1].z, (_Float16)br4[1].w };
    half8 g1 = { (_Float16)br4[2].x, (_Float16)br4[2].y, (_Float16)br4[2].z, (_Float16)br4[2].w,
                 (_Float16)br4[3].x, (_Float16)br4[3].y, (_Float16)br4[3].z, (_Float16)br4[3].w };
    _Float16* pb = &Bs[buf][ar][ac];
    *(half8*)pb = g0; *(half8*)(pb + 8) = g1;
  };

  gload(0);
  lwrite(0);
  const int NKT = DM / 32;
  for (int kt = 0; kt < NKT; ++kt) {
    __syncthreads();
    const int cur = kt & 1;
    if (kt + 1 < NKT) gload(kt + 1);
    half8 af[4], bf[4];
#pragma unroll
    for (int i = 0; i < 4; ++i) af[i] = *(const half8*)&As[cur][wm * 64 + i * 16 + lr][lg * 8];
#pragma unroll
    for (int j = 0; j < 4; ++j) bf[j] = *(const half8*)&Bs[cur][wn * 64 + j * 16 + lr][lg * 8];
#pragma unroll
    for (int i = 0; i < 4; ++i)
#pragma unroll
      for (int j = 0; j < 4; ++j)
        acc[i][j] = __builtin_amdgcn_mfma_f32_16x16x32_f16(af[i], bf[j], acc[i][j], 0, 0, 0);
    if (kt + 1 < NKT) lwrite((kt + 1) & 1);
  }

#pragma unroll
  for (int i = 0; i < 4; ++i) {
    const int m0 = bm * 128 + wm * 64 + i * 16 + lg * 4;
#pragma unroll
    for (int j = 0; j < 4; ++j) {
      const int gn = bn * 128 + wn * 64 + j * 16 + lr;
      const float bb = bias[gn];
#pragma unroll
      for (int r = 0; r < 4; ++r)
        Cout[(size_t)(m0 + r) * DM + gn] = acc[i][j][r] + bb;
    }
  }
}

// ---------------- flash attention v3 ----------------
// 256 blocks (XCD-grouped), 512 threads = 8 waves, wave = 16 q rows, KVB=64.
// Swapped QK^T (S^T), XOR-swizzled LDS, software-pipelined softmax, defer-max.
__global__ __launch_bounds__(512) void attn_kernel(
    const _Float16* __restrict__ Qp, const _Float16* __restrict__ Kc,
    const _Float16* __restrict__ Vt, _Float16* __restrict__ AO)
{
  __shared__ _Float16 Ks[2][64 * 128];
  __shared__ _Float16 VTs[3][128 * 64];
  __shared__ _Float16 Ps[8][16 * 64];

  const int tid = threadIdx.x;
  // XCD-grouped decode: 4 q-blocks of each (b,h) pair share an XCD
  const int lin = blockIdx.x;
  const int xcd = lin & 7, slot = lin >> 3;
  const int pair = xcd * 8 + (slot >> 2);
  const int qb = slot & 3;
  const int b = pair >> 4, h = pair & 15;
  const int q0 = qb * 128;

  const int wid = tid >> 6, lane = tid & 63;
  const int lr = lane & 15, lg = lane >> 4;
  const int qw = q0 + wid * 16;

  half8 qf[4];
#pragma unroll
  for (int kk = 0; kk < 4; ++kk)
    qf[kk] = *(const half8*)&Qp[(size_t)(b * SQ + qw + lr) * DM + h * DH + kk * 32 + lg * 8];

  f32x4 zero = {0.f, 0.f, 0.f, 0.f};
  f32x4 acc_t[8];
#pragma unroll
  for (int d = 0; d < 8; ++d) acc_t[d] = zero;
  float m_run = -1e30f, l_run = 0.f;

  const int nt = (CL + q0 + 128) / 64;
  const int kr = tid >> 4, kc = (tid & 15) << 3;   // K stage: rows 0..31(+32), 16B
  const int vr = tid >> 2, vc = (tid & 3) << 3;    // V stage: rows 0..127, 16B (+32 col)
  const _Float16* Kbase = Kc + (size_t)b * TT * DM + h * DH;
  const _Float16* Vbase = Vt + (size_t)(b * NH + h) * DH * TT;

  uint4 kreg0, kreg1, vreg0, vreg1;
  auto gload_t = [&](int tt) {
    const int t0 = tt * 64;
    kreg0 = *(const uint4*)(Kbase + (size_t)(t0 + kr) * DM + kc);
    kreg1 = *(const uint4*)(Kbase + (size_t)(t0 + kr + 32) * DM + kc);
    vreg0 = *(const uint4*)(Vbase + (size_t)vr * TT + t0 + vc);
    vreg1 = *(const uint4*)(Vbase + (size_t)vr * TT + t0 + 32 + vc);
  };
  auto lwrite_t = [&](int kbuf, int vbuf) {
    *(uint4*)&Ks[kbuf][KSW(kr, kc)] = kreg0;
    *(uint4*)&Ks[kbuf][KSW(kr + 32, kc)] = kreg1;
    *(uint4*)&VTs[vbuf][VSW(vr, vc)] = vreg0;
    *(uint4*)&VTs[vbuf][VSW(vr, vc + 32)] = vreg1;
  };

  auto qk = [&](int kbuf, f32x4* sc) {
#pragma unroll
    for (int j = 0; j < 4; ++j) {
      sc[j] = zero;
      half8 kb[4];
#pragma unroll
      for (int kk = 0; kk < 4; ++kk)
        kb[kk] = *(const half8*)&Ks[kbuf][KSW(j * 16 + lr, kk * 32 + lg * 8)];
#pragma unroll
      for (int kk = 0; kk < 4; ++kk)
        sc[j] = __builtin_amdgcn_mfma_f32_16x16x32_f16(kb[kk], qf[kk], sc[j], 0, 0, 0);
    }
  };

  auto mask_s = [&](int t0, f32x4* sc) {
    if (t0 + 63 > CL + qw) {
#pragma unroll
      for (int j = 0; j < 4; ++j)
#pragma unroll
        for (int r = 0; r < 4; ++r)
          if (t0 + j * 16 + lg * 4 + r > CL + qw + lr) sc[j][r] = -1e30f;
    }
  };

  auto softmax_step = [&](f32x4* sp) {
    float mt = sp[0][0];
#pragma unroll
    for (int j = 0; j < 4; ++j)
#pragma unroll
      for (int r = 0; r < 4; ++r) mt = fmaxf(mt, sp[j][r]);
    mt = fmaxf(mt, __shfl_xor(mt, 16));
    mt = fmaxf(mt, __shfl_xor(mt, 32));
    if (!__all(mt <= m_run + 10.0f)) {
      const float mn = fmaxf(m_run, mt);
      const float fsc = exp2f(m_run - mn);
      m_run = mn;
      l_run *= fsc;
#pragma unroll
      for (int d = 0; d < 8; ++d)
#pragma unroll
        for (int r = 0; r < 4; ++r) acc_t[d][r] *= fsc;
    }
    float ps = 0.f;
#pragma unroll
    for (int j = 0; j < 4; ++j) {
      float p0 = exp2f(sp[j][0] - m_run);
      float p1 = exp2f(sp[j][1] - m_run);
      float p2 = exp2f(sp[j][2] - m_run);
      float p3 = exp2f(sp[j][3] - m_run);
      ps += (p0 + p1) + (p2 + p3);
      half4v hp = { (_Float16)p0, (_Float16)p1, (_Float16)p2, (_Float16)p3 };
      *(half4v*)&Ps[wid][PSW(lr, j * 16 + lg * 4)] = hp;
    }
    ps += __shfl_xor(ps, 16);
    ps += __shfl_xor(ps, 32);
    l_run += ps;
  };

  auto pv = [&](int vbuf) {
#pragma unroll
    for (int tf = 0; tf < 2; ++tf) {
      half8 pf = *(const half8*)&Ps[wid][PSW(lr, tf * 32 + lg * 8)];
#pragma unroll
      for (int d = 0; d < 8; ++d) {
        half8 vf = *(const half8*)&VTs[vbuf][VSW(d * 16 + lr, tf * 32 + lg * 8)];
        acc_t[d] = __builtin_amdgcn_mfma_f32_16x16x32_f16(vf, pf, acc_t[d], 0, 0, 0);
      }
    }
  };

  f32x4 sp[4], sc[4];

  // prologue: tile 0 staged, tile 1 in flight, QK(0)
  gload_t(0);
  lwrite_t(0, 0);
  __syncthreads();
  gload_t(1);
  qk(0, sp);
  mask_s(0, sp);
  lwrite_t(1, 1);

  for (int t = 1; t < nt; ++t) {
    __syncthreads();
    if (t + 1 < nt) gload_t(t + 1);
    qk(t & 1, sc);        // MFMA for tile t in flight...
    softmax_step(sp);     // ...while VALU finishes tile t-1
    pv((t - 1) % 3);
    mask_s(t * 64, sc);
#pragma unroll
    for (int j = 0; j < 4; ++j) sp[j] = sc[j];
    if (t + 1 < nt) lwrite_t((t + 1) & 1, (t + 1) % 3);
  }
  softmax_step(sp);
  pv((nt - 1) % 3);

  const float inv = 1.0f / l_run;
#pragma unroll
  for (int d = 0; d < 8; ++d) {
    half4v hv;
#pragma unroll
    for (int r = 0; r < 4; ++r) hv[r] = (_Float16)(acc_t[d][r] * inv);
    *(half4v*)&AO[(size_t)(b * SQ + qw + lr) * DM + h * DH + d * 16 + lg * 4] = hv;
  }
}

extern "C" void kernel_launch(void* const* d_in, const int* in_sizes, int n_in,
                              void* d_out, int out_size, void* d_ws, size_t ws_size,
                              hipStream_t stream) {
  const float* query = (const float*)d_in[0];
  const float* key   = (const float*)d_in[1];
  const float* value = (const float*)d_in[2];
  const float* ck    = (const float*)d_in[3];
  const float* cv    = (const float*)d_in[4];
  const float* wq = (const float*)d_in[5];
  const float* bq = (const float*)d_in[6];
  const float* wk = (const float*)d_in[7];
  const float* bk = (const float*)d_in[8];
  const float* wv = (const float*)d_in[9];
  const float* bv = (const float*)d_in[10];
  const float* wo = (const float*)d_in[11];
  const float* bo = (const float*)d_in[12];

  char* ws = (char*)d_ws;
  _Float16* Kc = (_Float16*)ws;                 // 64 MiB: [4][4096][2048]
  _Float16* Vt = (_Float16*)(ws + 67108864);    // 64 MiB: [4][16][128][4096]
  _Float16* Qp = (_Float16*)(ws + 134217728);   // 8 MiB
  _Float16* AO = (_Float16*)(ws + 142606336);   // 8 MiB

  convert_K<<<dim3(2048), dim3(256), 0, stream>>>(ck, Kc);
  transpose_V<<<dim3(CL / 64, DM / 64, NB), dim3(256), 0, stream>>>(cv, Vt);
  qkv_gemm<<<dim3(16, 16, 3), dim3(256), 0, stream>>>(
      query, key, value, wq, wk, wv, bq, bk, bv, Qp, Kc, Vt);
  attn_kernel<<<dim3(256), dim3(512), 0, stream>>>(Qp, Kc, Vt, AO);
  o_gemm<<<dim3(16, 16), dim3(256), 0, stream>>>(AO, wo, bo, (float*)d_out);
}

// Round 4
// 319.603 us; speedup vs baseline: 2.1073x; 1.2646x over previous
//
#include <hip/hip_runtime.h>

typedef _Float16 half8 __attribute__((ext_vector_type(8)));
typedef _Float16 half4v __attribute__((ext_vector_type(4)));
typedef float f32x4 __attribute__((ext_vector_type(4)));

#define NB 4
#define SQ 512
#define CL 3584
#define TT 4096
#define DM 2048
#define NH 16
#define DH 128

// XOR swizzles on half-index (attn LDS)
#define KSW(row, col) ((((row) * 128) + (col)) ^ ((((row) & 7) << 3)))
#define VSW(row, col) ((((row) * 64) + (col)) ^ ((((row) & 7) << 3)))
#define PSW(row, col) ((((row) * 64) + (col)) ^ ((((row) & 7) << 3)))

__device__ __forceinline__ void gl_lds16(const void* g, void* l) {
  __builtin_amdgcn_global_load_lds(
      (const __attribute__((address_space(1))) unsigned int*)g,
      (__attribute__((address_space(3))) unsigned int*)l, 16, 0, 0);
}

// ---------------- generic fp32 -> f16 convert (3 segments, strided dst) ----------------
__global__ __launch_bounds__(256) void cvt_f16(
    const float* __restrict__ s0, const float* __restrict__ s1, const float* __restrict__ s2,
    _Float16* __restrict__ d0, _Float16* __restrict__ d1, _Float16* __restrict__ d2,
    int dstride)  // dst row stride in halves (row = 2048 elements)
{
  const float* s = blockIdx.y == 0 ? s0 : blockIdx.y == 1 ? s1 : s2;
  _Float16* d = blockIdx.y == 0 ? d0 : blockIdx.y == 1 ? d1 : d2;
  const int n4 = DM * DM / 4;
  for (int v = blockIdx.x * blockDim.x + threadIdx.x; v < n4;
       v += gridDim.x * blockDim.x) {
    float4 x = ((const float4*)s)[v];
    half4v h = { (_Float16)x.x, (_Float16)x.y, (_Float16)x.z, (_Float16)x.w };
    const int m = v >> 9, c = (v << 2) & 2047;
    *(half4v*)&d[(size_t)m * dstride + c] = h;
  }
}

// ---------------- cached K fp32 -> f16 linear convert ----------------
__global__ __launch_bounds__(256) void convert_K(
    const float* __restrict__ ck, _Float16* __restrict__ K)
{
  const long long nvec = (long long)NB * CL * DM / 4;
  const int pb = CL * DM / 4;
  for (long long v = (long long)blockIdx.x * blockDim.x + threadIdx.x; v < nvec;
       v += (long long)gridDim.x * blockDim.x) {
    int b = (int)(v / pb);
    long long r = v - (long long)b * pb;
    float4 x = ((const float4*)ck)[v];
    half4v hx = { (_Float16)x.x, (_Float16)x.y, (_Float16)x.z, (_Float16)x.w };
    ((half4v*)K)[(long long)b * (TT * DM / 4) + r] = hx;
  }
}

// ---------------- cached V fp32 -> f16 transpose: Vt[b][h][d][t] ----------------
__global__ __launch_bounds__(256) void transpose_V(
    const float* __restrict__ cv, _Float16* __restrict__ Vt)
{
  __shared__ _Float16 T[64][70];
  const int t0 = blockIdx.x * 64;
  const int dm0 = blockIdx.y * 64;
  const int b = blockIdx.z;
  const int tid = threadIdx.x;
  {
    const int tr = tid >> 2, c0 = (tid & 3) * 16;
    const float* src = cv + ((size_t)b * CL + t0 + tr) * DM + dm0 + c0;
    float4 a0 = ((const float4*)src)[0];
    float4 a1 = ((const float4*)src)[1];
    float4 a2 = ((const float4*)src)[2];
    float4 a3 = ((const float4*)src)[3];
    half8 h0 = { (_Float16)a0.x, (_Float16)a0.y, (_Float16)a0.z, (_Float16)a0.w,
                 (_Float16)a1.x, (_Float16)a1.y, (_Float16)a1.z, (_Float16)a1.w };
    half8 h1 = { (_Float16)a2.x, (_Float16)a2.y, (_Float16)a2.z, (_Float16)a2.w,
                 (_Float16)a3.x, (_Float16)a3.y, (_Float16)a3.z, (_Float16)a3.w };
    *(half8*)&T[tr][c0] = h0;
    *(half8*)&T[tr][c0 + 8] = h1;
  }
  __syncthreads();
  {
    const int dl = tid >> 2, tc = (tid & 3) * 16;
    const int h = dm0 >> 7, d = (dm0 & 127) + dl;
    half8 o0, o1;
#pragma unroll
    for (int i = 0; i < 8; ++i) o0[i] = T[tc + i][dl];
#pragma unroll
    for (int i = 0; i < 8; ++i) o1[i] = T[tc + 8 + i][dl];
    _Float16* dst = Vt + ((size_t)(b * NH + h) * DH + d) * TT + t0 + tc;
    *(half8*)dst = o0;
    *(half8*)(dst + 8) = o1;
  }
}

// ---------------- f16 GEMM via global_load_lds, 128x128 tile, BK=32, 8 waves ----------------
// LDS tiles: A 128x(32 f16) = 8KB, W 128x(32 f16) = 8KB, double buffered (32 KB).
// Tile rows paired into 128B LDS rows; byte swizzle within the 128B row:
//   phys(r,cb) = (r>>1)*128 + ((((r&1)<<6)|cb) ^ (((r>>1)&7)<<4))
// global_load_lds writes linearly; the per-lane GLOBAL source is pre-unswizzled.
// MODE 0: QKV (z=0 Q scale->Qp, z=1 K scatter->Kc, z=2 V scatter->Vt)
// MODE 1: O projection (fp32 out + bias)
template<int MODE>
__global__ __launch_bounds__(512, 4) void mm16(
    const _Float16* __restrict__ A0, const _Float16* __restrict__ A1,
    const _Float16* __restrict__ A2, int astride,  // A row stride in BYTES
    const _Float16* __restrict__ W0, const _Float16* __restrict__ W1,
    const _Float16* __restrict__ W2,
    const float* __restrict__ b0, const float* __restrict__ b1,
    const float* __restrict__ b2,
    _Float16* __restrict__ Qp, _Float16* __restrict__ Kc,
    _Float16* __restrict__ Vt, float* __restrict__ Co)
{
  __shared__ __align__(16) char smem[4 * 8192];
  char* Abuf = smem;              // 2 x 8KB
  char* Wbuf = smem + 2 * 8192;   // 2 x 8KB

  const int tid = threadIdx.x;
  const int bm = blockIdx.x, bn = blockIdx.y, z = blockIdx.z;
  const _Float16* Ain = z == 0 ? A0 : z == 1 ? A1 : A2;
  const _Float16* W   = z == 0 ? W0 : z == 1 ? W1 : W2;
  const float* bias   = z == 0 ? b0 : z == 1 ? b1 : b2;

  const int wid = tid >> 6, lane = tid & 63;
  const int wm = wid >> 2, wn = wid & 3;   // wave tile: rows wm*64, cols wn*32
  const int lr = lane & 15, lg = lane >> 4;

  f32x4 acc[4][2];
#pragma unroll
  for (int i = 0; i < 4; ++i)
#pragma unroll
    for (int j = 0; j < 2; ++j) acc[i][j] = (f32x4){0.f, 0.f, 0.f, 0.f};

  // per-lane staging source offsets (bytes), derived from linear LDS offset
  size_t aoff, woff;
  {
    const int o = wid * 1024 + lane * 16;
    const int prow = o >> 7, pb = o & 127;
    const int lb = pb ^ ((prow & 7) << 4);
    const int r = (prow << 1) | (lb >> 6), c = lb & 63;
    aoff = (size_t)(bm * 128 + r) * astride + c;
    woff = (size_t)(bn * 128 + r) * 4096 + c;
  }

  auto stage = [&](int kt, int buf) {
    gl_lds16((const char*)Ain + aoff + kt * 64, Abuf + buf * 8192 + wid * 1024);
    gl_lds16((const char*)W + woff + kt * 64, Wbuf + buf * 8192 + wid * 1024);
  };

  auto lds_addr = [](const char* base, int r, int cb) -> const char* {
    return base + ((r >> 1) << 7) + ((((r & 1) << 6) | cb) ^ (((r >> 1) & 7) << 4));
  };

  auto compute = [&](int buf) {
    const char* ab = Abuf + buf * 8192;
    const char* wb = Wbuf + buf * 8192;
    half8 af[4], bf[2];
#pragma unroll
    for (int i = 0; i < 4; ++i)
      af[i] = *(const half8*)lds_addr(ab, wm * 64 + i * 16 + lr, lg << 4);
#pragma unroll
    for (int j = 0; j < 2; ++j)
      bf[j] = *(const half8*)lds_addr(wb, wn * 32 + j * 16 + lr, lg << 4);
#pragma unroll
    for (int i = 0; i < 4; ++i)
#pragma unroll
      for (int j = 0; j < 2; ++j)
        acc[i][j] = __builtin_amdgcn_mfma_f32_16x16x32_f16(af[i], bf[j], acc[i][j], 0, 0, 0);
  };

  const int NKT = DM / 32;  // 64
  stage(0, 0);
  __syncthreads();
  for (int kt = 0; kt < NKT; ++kt) {
    if (kt + 1 < NKT) stage(kt + 1, (kt + 1) & 1);
    compute(kt & 1);
    __syncthreads();
  }

  const float qscale = 0.08838834764831845f * 1.4426950408889634f;
#pragma unroll
  for (int i = 0; i < 4; ++i) {
    const int m0 = bm * 128 + wm * 64 + i * 16 + lg * 4;
#pragma unroll
    for (int j = 0; j < 2; ++j) {
      const int gn = bn * 128 + wn * 32 + j * 16 + lr;
      const float bb = bias[gn];
      if constexpr (MODE == 1) {
#pragma unroll
        for (int r = 0; r < 4; ++r)
          Co[(size_t)(m0 + r) * DM + gn] = acc[i][j][r] + bb;
      } else {
        if (z == 0) {
#pragma unroll
          for (int r = 0; r < 4; ++r)
            Qp[(size_t)(m0 + r) * DM + gn] = (_Float16)((acc[i][j][r] + bb) * qscale);
        } else if (z == 1) {
          const int b = m0 >> 9;
#pragma unroll
          for (int r = 0; r < 4; ++r)
            Kc[((size_t)b * TT + CL + ((m0 + r) & 511)) * DM + gn] =
                (_Float16)(acc[i][j][r] + bb);
        } else {
          half4v hv;
#pragma unroll
          for (int r = 0; r < 4; ++r) hv[r] = (_Float16)(acc[i][j][r] + bb);
          const int b = m0 >> 9, t = CL + (m0 & 511);
          const int h = gn >> 7, d = gn & 127;
          *(half4v*)&Vt[((size_t)(b * NH + h) * DH + d) * TT + t] = hv;
        }
      }
    }
  }
}

// ---------------- flash attention (unchanged from R3) ----------------
__global__ __launch_bounds__(512) void attn_kernel(
    const _Float16* __restrict__ Qp, const _Float16* __restrict__ Kc,
    const _Float16* __restrict__ Vt, _Float16* __restrict__ AO)
{
  __shared__ _Float16 Ks[2][64 * 128];
  __shared__ _Float16 VTs[3][128 * 64];
  __shared__ _Float16 Ps[8][16 * 64];

  const int tid = threadIdx.x;
  const int lin = blockIdx.x;
  const int xcd = lin & 7, slot = lin >> 3;
  const int pair = xcd * 8 + (slot >> 2);
  const int qb = slot & 3;
  const int b = pair >> 4, h = pair & 15;
  const int q0 = qb * 128;

  const int wid = tid >> 6, lane = tid & 63;
  const int lr = lane & 15, lg = lane >> 4;
  const int qw = q0 + wid * 16;

  half8 qf[4];
#pragma unroll
  for (int kk = 0; kk < 4; ++kk)
    qf[kk] = *(const half8*)&Qp[(size_t)(b * SQ + qw + lr) * DM + h * DH + kk * 32 + lg * 8];

  f32x4 zero = {0.f, 0.f, 0.f, 0.f};
  f32x4 acc_t[8];
#pragma unroll
  for (int d = 0; d < 8; ++d) acc_t[d] = zero;
  float m_run = -1e30f, l_run = 0.f;

  const int nt = (CL + q0 + 128) / 64;
  const int kr = tid >> 4, kc = (tid & 15) << 3;
  const int vr = tid >> 2, vc = (tid & 3) << 3;
  const _Float16* Kbase = Kc + (size_t)b * TT * DM + h * DH;
  const _Float16* Vbase = Vt + (size_t)(b * NH + h) * DH * TT;

  uint4 kreg0, kreg1, vreg0, vreg1;
  auto gload_t = [&](int tt) {
    const int t0 = tt * 64;
    kreg0 = *(const uint4*)(Kbase + (size_t)(t0 + kr) * DM + kc);
    kreg1 = *(const uint4*)(Kbase + (size_t)(t0 + kr + 32) * DM + kc);
    vreg0 = *(const uint4*)(Vbase + (size_t)vr * TT + t0 + vc);
    vreg1 = *(const uint4*)(Vbase + (size_t)vr * TT + t0 + 32 + vc);
  };
  auto lwrite_t = [&](int kbuf, int vbuf) {
    *(uint4*)&Ks[kbuf][KSW(kr, kc)] = kreg0;
    *(uint4*)&Ks[kbuf][KSW(kr + 32, kc)] = kreg1;
    *(uint4*)&VTs[vbuf][VSW(vr, vc)] = vreg0;
    *(uint4*)&VTs[vbuf][VSW(vr, vc + 32)] = vreg1;
  };

  auto qk = [&](int kbuf, f32x4* sc) {
#pragma unroll
    for (int j = 0; j < 4; ++j) {
      sc[j] = zero;
      half8 kb[4];
#pragma unroll
      for (int kk = 0; kk < 4; ++kk)
        kb[kk] = *(const half8*)&Ks[kbuf][KSW(j * 16 + lr, kk * 32 + lg * 8)];
#pragma unroll
      for (int kk = 0; kk < 4; ++kk)
        sc[j] = __builtin_amdgcn_mfma_f32_16x16x32_f16(kb[kk], qf[kk], sc[j], 0, 0, 0);
    }
  };

  auto mask_s = [&](int t0, f32x4* sc) {
    if (t0 + 63 > CL + qw) {
#pragma unroll
      for (int j = 0; j < 4; ++j)
#pragma unroll
        for (int r = 0; r < 4; ++r)
          if (t0 + j * 16 + lg * 4 + r > CL + qw + lr) sc[j][r] = -1e30f;
    }
  };

  auto softmax_step = [&](f32x4* sp) {
    float mt = sp[0][0];
#pragma unroll
    for (int j = 0; j < 4; ++j)
#pragma unroll
      for (int r = 0; r < 4; ++r) mt = fmaxf(mt, sp[j][r]);
    mt = fmaxf(mt, __shfl_xor(mt, 16));
    mt = fmaxf(mt, __shfl_xor(mt, 32));
    if (!__all(mt <= m_run + 10.0f)) {
      const float mn = fmaxf(m_run, mt);
      const float fsc = exp2f(m_run - mn);
      m_run = mn;
      l_run *= fsc;
#pragma unroll
      for (int d = 0; d < 8; ++d)
#pragma unroll
        for (int r = 0; r < 4; ++r) acc_t[d][r] *= fsc;
    }
    float ps = 0.f;
#pragma unroll
    for (int j = 0; j < 4; ++j) {
      float p0 = exp2f(sp[j][0] - m_run);
      float p1 = exp2f(sp[j][1] - m_run);
      float p2 = exp2f(sp[j][2] - m_run);
      float p3 = exp2f(sp[j][3] - m_run);
      ps += (p0 + p1) + (p2 + p3);
      half4v hp = { (_Float16)p0, (_Float16)p1, (_Float16)p2, (_Float16)p3 };
      *(half4v*)&Ps[wid][PSW(lr, j * 16 + lg * 4)] = hp;
    }
    ps += __shfl_xor(ps, 16);
    ps += __shfl_xor(ps, 32);
    l_run += ps;
  };

  auto pv = [&](int vbuf) {
#pragma unroll
    for (int tf = 0; tf < 2; ++tf) {
      half8 pf = *(const half8*)&Ps[wid][PSW(lr, tf * 32 + lg * 8)];
#pragma unroll
      for (int d = 0; d < 8; ++d) {
        half8 vf = *(const half8*)&VTs[vbuf][VSW(d * 16 + lr, tf * 32 + lg * 8)];
        acc_t[d] = __builtin_amdgcn_mfma_f32_16x16x32_f16(vf, pf, acc_t[d], 0, 0, 0);
      }
    }
  };

  f32x4 sp[4], sc[4];

  gload_t(0);
  lwrite_t(0, 0);
  __syncthreads();
  gload_t(1);
  qk(0, sp);
  mask_s(0, sp);
  lwrite_t(1, 1);

  for (int t = 1; t < nt; ++t) {
    __syncthreads();
    if (t + 1 < nt) gload_t(t + 1);
    qk(t & 1, sc);
    softmax_step(sp);
    pv((t - 1) % 3);
    mask_s(t * 64, sc);
#pragma unroll
    for (int j = 0; j < 4; ++j) sp[j] = sc[j];
    if (t + 1 < nt) lwrite_t((t + 1) & 1, (t + 1) % 3);
  }
  softmax_step(sp);
  pv((nt - 1) % 3);

  const float inv = 1.0f / l_run;
#pragma unroll
  for (int d = 0; d < 8; ++d) {
    half4v hv;
#pragma unroll
    for (int r = 0; r < 4; ++r) hv[r] = (_Float16)(acc_t[d][r] * inv);
    *(half4v*)&AO[(size_t)(b * SQ + qw + lr) * DM + h * DH + d * 16 + lg * 4] = hv;
  }
}

extern "C" void kernel_launch(void* const* d_in, const int* in_sizes, int n_in,
                              void* d_out, int out_size, void* d_ws, size_t ws_size,
                              hipStream_t stream) {
  const float* query = (const float*)d_in[0];
  const float* key   = (const float*)d_in[1];
  const float* value = (const float*)d_in[2];
  const float* ck    = (const float*)d_in[3];
  const float* cv    = (const float*)d_in[4];
  const float* wq = (const float*)d_in[5];
  const float* bq = (const float*)d_in[6];
  const float* wk = (const float*)d_in[7];
  const float* bk = (const float*)d_in[8];
  const float* wv = (const float*)d_in[9];
  const float* bv = (const float*)d_in[10];
  const float* wo = (const float*)d_in[11];
  const float* bo = (const float*)d_in[12];

  char* ws = (char*)d_ws;
  _Float16* Kc = (_Float16*)ws;                 // 64 MiB: [4][4096][2048]
  _Float16* Vt = (_Float16*)(ws + 67108864);    // 64 MiB: [4][16][128][4096]
  _Float16* Qp = (_Float16*)(ws + 134217728);   // 8 MiB
  _Float16* AO = (_Float16*)(ws + 142606336);   // 8 MiB

  // transient f16 tensors aliased into dead regions (overwritten later):
  // wq/wk/wv f16 in Kc's cache-row spans (convert_K rewrites them after qkv);
  // q/k/v f16 in first 4KB of Vt rows (transpose_V rewrites them after qkv);
  // wo f16 in Qp (converted after attn has consumed Qp).
  _Float16* wqh = Kc;
  _Float16* wkh = Kc + 8388608;    // byte 16 MiB
  _Float16* wvh = Kc + 16777216;   // byte 32 MiB
  _Float16* qh = Vt;               // rows at stride 8192 B
  _Float16* kh = Vt + 2048 * 4096;
  _Float16* vh = Vt + 4096 * 4096;
  _Float16* woh = Qp;

  cvt_f16<<<dim3(512, 3), 256, 0, stream>>>(query, key, value, qh, kh, vh, 4096);
  cvt_f16<<<dim3(512, 3), 256, 0, stream>>>(wq, wk, wv, wqh, wkh, wvh, 2048);
  mm16<0><<<dim3(16, 16, 3), 512, 0, stream>>>(
      qh, kh, vh, 8192, wqh, wkh, wvh, bq, bk, bv, Qp, Kc, Vt, nullptr);
  convert_K<<<2048, 256, 0, stream>>>(ck, Kc);
  transpose_V<<<dim3(CL / 64, DM / 64, NB), 256, 0, stream>>>(cv, Vt);
  attn_kernel<<<256, 512, 0, stream>>>(Qp, Kc, Vt, AO);
  cvt_f16<<<dim3(512, 1), 256, 0, stream>>>(wo, wo, wo, woh, woh, woh, 2048);
  mm16<1><<<dim3(16, 16, 1), 512, 0, stream>>>(
      AO, AO, AO, 4096, woh, woh, woh, bo, bo, bo, nullptr, nullptr, nullptr,
      (float*)d_out);
}